// Round 2
// baseline (282.271 us; speedup 1.0000x reference)
//
#include <hip/hip_runtime.h>
#include <hip/hip_bf16.h>
#include <cstdint>
#include <cstddef>

typedef __bf16 bf16x8 __attribute__((ext_vector_type(8)));
typedef float  f32x4  __attribute__((ext_vector_type(4)));

__device__ __forceinline__ unsigned short f2bf(float f) {
    __hip_bfloat16 b = __float2bfloat16(f);
    return *reinterpret_cast<unsigned short*>(&b);
}

// fast GELU (tanh form), ~7 VALU ops, saturation-safe:
// g = x / (1 + exp2(x*(-2.30220795 - 0.10294314 x^2)))
__device__ __forceinline__ float fast_gelu(float x) {
    float x2 = x * x;
    float m  = x * __builtin_fmaf(x2, -0.10294314f, -2.30220795f);
    float e  = __builtin_amdgcn_exp2f(m);
    return x * __builtin_amdgcn_rcpf(1.0f + e);
}

// ---------------- aux kernels (unchanged) ----------------

__global__ void abs_sum_cvt_kernel(const float4* __restrict__ w0, const float4* __restrict__ w1,
                                   int n4w, float* __restrict__ part,
                                   const float4* __restrict__ x, ushort4* __restrict__ xb,
                                   int n4x) {
    int seg = (int)blockIdx.x >> 9;                // 0,1,2
    int b = (int)blockIdx.x & 511;
    if (seg == 2) {
        for (int i = b * blockDim.x + threadIdx.x; i < n4x; i += 512 * blockDim.x) {
            float4 v = x[i];
            ushort4 o;
            o.x = f2bf(v.x); o.y = f2bf(v.y); o.z = f2bf(v.z); o.w = f2bf(v.w);
            xb[i] = o;
        }
        return;
    }
    const float4* w = seg ? w1 : w0;
    float s = 0.0f;
    for (int i = b * blockDim.x + threadIdx.x; i < n4w; i += 512 * blockDim.x) {
        float4 v = w[i];
        s += fabsf(v.x) + fabsf(v.y) + fabsf(v.z) + fabsf(v.w);
    }
    #pragma unroll
    for (int o = 32; o > 0; o >>= 1) s += __shfl_down(s, o, 64);
    __shared__ float ps[4];
    int lane = threadIdx.x & 63, wid = threadIdx.x >> 6;
    if (lane == 0) ps[wid] = s;
    __syncthreads();
    if (threadIdx.x == 0) part[blockIdx.x] = ps[0] + ps[1] + ps[2] + ps[3];
}

__global__ void ternarize_kernel(const float4* __restrict__ w0, ushort4* __restrict__ t0,
                                 const float4* __restrict__ w1, ushort4* __restrict__ t1,
                                 int n4w, const float* __restrict__ part, float inv_n) {
    int seg = (int)blockIdx.x >> 10;               // 0 or 1
    int b = (int)blockIdx.x & 1023;

    float s = 0.0f;
    for (int j = threadIdx.x; j < 512; j += 256) s += part[seg * 512 + j];
    #pragma unroll
    for (int o = 32; o > 0; o >>= 1) s += __shfl_down(s, o, 64);
    __shared__ float ps[4];
    __shared__ float sscale;
    int lane = threadIdx.x & 63, wid = threadIdx.x >> 6;
    if (lane == 0) ps[wid] = s;
    __syncthreads();
    if (threadIdx.x == 0) {
        float tot = ps[0] + ps[1] + ps[2] + ps[3];
        sscale = fmaxf(tot * inv_n, 1e-8f);
    }
    __syncthreads();
    float inv = 1.0f / sscale;

    const float4* w = seg ? w1 : w0;
    ushort4* t = seg ? t1 : t0;
    for (int i = b * blockDim.x + threadIdx.x; i < n4w; i += 1024 * blockDim.x) {
        float4 v = w[i];
        ushort4 o;
        o.x = f2bf(fminf(fmaxf(rintf(v.x * inv), -1.0f), 1.0f));
        o.y = f2bf(fminf(fmaxf(rintf(v.y * inv), -1.0f), 1.0f));
        o.z = f2bf(fminf(fmaxf(rintf(v.z * inv), -1.0f), 1.0f));
        o.w = f2bf(fminf(fmaxf(rintf(v.w * inv), -1.0f), 1.0f));
        t[i] = o;
    }
}

// ---------------- 8-phase GEMM with fragment READ-AHEAD ----------------
// NT: C[m][n] = sum_k A[m][k]*B[n][k].  BM=256, BK=64, 512 thr = 8 waves, dbuf LDS.
//
// Key change vs prior round: each phase issues the ds_reads for the NEXT
// phase's MFMA quadrant; the pre-MFMA wait is a COUNTED lgkmcnt(#issued this
// phase), so the previous batch (this phase's operands) is guaranteed done
// while the new batch drains during this phase's MFMA.  Quadrant order
// alternates per tile -- even: (0,0),(1,0),(1,1),(0,1); odd: (1,0),(0,0),
// (0,1),(1,1) -- which makes every read-ahead target a frag register that is
// NOT an operand of the current phase's MFMA (no WAR, no extra frag buffers).
//
// Per-phase read batches (GEMM1): {8,4,4,8, 8,4,4,8} per 2 K-tiles.
// Stage stream (1 half-tile/phase): p1 B0(t+1), p2 B1(t+1), p3 A0(t+2),
// p4 A1(t+2), p5 B0(t+2), p6 B1(t+2), p7 A0(t+3), p8 A1(t+3).
// Counted vmcnt waits sit BEFORE a closing barrier (publication: wave drains
// its own portion, barrier publishes all waves' portions, dependent ds_read
// comes after):  p1-end vm(4+SBL) -> B1(2it) for p2;  p2-end vm(SBL) ->
// A(2it+1)+B0(2it+1) for p3/p4/p5;  p5-end vm(4+SBL) -> B1(2it+1) for p6;
// p6-end vm(SBL) -> A(2it+2)+B0(2it+2) for p7/p8/p1'.  (SBL = loads per
// B half-tile = 2 for BN=256, 1 for BN=128.)  Never vmcnt(0) in the loop.
// LDS 16B-chunk XOR swizzle via pre-swizzled GLOBAL source column (dest of
// global_load_lds stays linear); reads use same XOR -> zero bank conflicts.

#define GLL(SRC, DST) __builtin_amdgcn_global_load_lds( \
    (const __attribute__((address_space(1))) void*)(SRC), \
    (__attribute__((address_space(3))) void*)(DST), 16, 0, 0)

#define BAR() do { asm volatile("" ::: "memory"); \
    __builtin_amdgcn_sched_barrier(0); \
    __builtin_amdgcn_s_barrier(); \
    __builtin_amdgcn_sched_barrier(0); \
    asm volatile("" ::: "memory"); } while (0)

#define WLG_N(NN) do { asm volatile("s_waitcnt lgkmcnt(" #NN ")" ::: "memory"); \
    __builtin_amdgcn_sched_barrier(0); } while (0)
#define WVM_N(NN) do { asm volatile("s_waitcnt vmcnt(" #NN ")" ::: "memory"); \
    __builtin_amdgcn_sched_barrier(0); } while (0)

// wait = #ds_reads issued this phase (drains previous phase's batch)
#define WLG_A() do { if constexpr (MF2 == 4) WLG_N(8); else WLG_N(4); } while (0)
#define WLG_B() WLG_N(4)
// vm waits: see header comment
#define WVM_B1()   do { if constexpr (SBL == 2) WVM_N(6); else WVM_N(5); } while (0)
#define WVM_HALF() do { if constexpr (SBL == 2) WVM_N(2); else WVM_N(1); } while (0)

#define LDA(MS, BUF) do { \
    _Pragma("unroll") \
    for (int f_ = 0; f_ < MF2; ++f_) { \
        const unsigned short* p_ = &As[(BUF)*16384 + AH*8192 + (rA0 + (MS)*(WM/2) + f_*16 + lr)*64]; \
        av[MS][f_][0] = *(const bf16x8*)(p_ + swz0); \
        av[MS][f_][1] = *(const bf16x8*)(p_ + swz1); \
    } \
} while (0)

#define LDB(NS, BUF) do { \
    _Pragma("unroll") \
    for (int g_ = 0; g_ < NF2; ++g_) { \
        const unsigned short* p_ = &Bs[(BUF)*(BN*64) + BHw*(BH*64) + (rB0 + (NS)*32 + g_*16 + lr)*64]; \
        bv[NS][g_][0] = *(const bf16x8*)(p_ + swz0); \
        bv[NS][g_][1] = *(const bf16x8*)(p_ + swz1); \
    } \
} while (0)

#define MMA(MS, NS) do { \
    __builtin_amdgcn_s_setprio(1); \
    _Pragma("unroll") \
    for (int f_ = 0; f_ < MF2; ++f_) { \
        _Pragma("unroll") \
        for (int g_ = 0; g_ < NF2; ++g_) { \
            acc[(MS)*MF2 + f_][(NS)*NF2 + g_] = __builtin_amdgcn_mfma_f32_16x16x32_bf16( \
                av[MS][f_][0], bv[NS][g_][0], acc[(MS)*MF2 + f_][(NS)*NF2 + g_], 0, 0, 0); \
            acc[(MS)*MF2 + f_][(NS)*NF2 + g_] = __builtin_amdgcn_mfma_f32_16x16x32_bf16( \
                av[MS][f_][1], bv[NS][g_][1], acc[(MS)*MF2 + f_][(NS)*NF2 + g_], 0, 0, 0); \
        } \
    } \
    __builtin_amdgcn_s_setprio(0); \
} while (0)

#define STAGE_A(BUF, H, T) do { \
    const unsigned short* s_ = pA + (size_t)((H)*128)*K + (((T) & (KT-1)) << 6); \
    GLL(s_,                 &As[(BUF)*16384 + (H)*8192 + tid*8]); \
    GLL(s_ + (size_t)64*K,  &As[(BUF)*16384 + (H)*8192 + 4096 + tid*8]); \
} while (0)

#define STAGE_B(BUF, H, T) do { \
    const unsigned short* s_ = pB + (size_t)((H)*BH)*K + (((T) & (KT-1)) << 6); \
    GLL(s_, &Bs[(BUF)*(BN*64) + (H)*(BH*64) + tid*8]); \
    if constexpr (BN == 256) { \
        GLL(s_ + (size_t)64*K, &Bs[(BUF)*(BN*64) + (H)*(BH*64) + 4096 + tid*8]); \
    } \
} while (0)

// EPI==0: C = bf16, bias + fast GELU.  EPI==1: C = fp32, bias.
// BN=256 -> waves 2Mx4N (wave tile 128x64).  BN=128 -> waves 4Mx2N (64x64).
template <int EPI, int K, int N, int BN, int WM>
__global__ __launch_bounds__(512, 2)
void gemm8p_kernel(const unsigned short* __restrict__ A,
                   const unsigned short* __restrict__ B,
                   const float* __restrict__ bias,
                   void* __restrict__ C) {
    constexpr int BM = 256;
    constexpr int WN = 64;
    constexpr int WARPS_N = BN / WN;           // 4 or 2
    constexpr int MF = WM / 16;                // 8 or 4
    constexpr int NF = WN / 16;                // 4
    constexpr int MF2 = MF / 2;                // 4 or 2
    constexpr int NF2 = NF / 2;                // 2
    constexpr int BH = (BN == 256) ? 128 : 64; // rows per B half-tile
    constexpr int SBL = (BN == 256) ? 2 : 1;   // loads per B half-tile stage
    constexpr int KT = K / 64;                 // K-tiles (power of 2)
    constexpr int NBX = N / BN;
    static_assert((BM / WM) * WARPS_N == 8, "8 waves");
    static_assert((KT & (KT - 1)) == 0, "KT pow2");

    __shared__ __align__(16) unsigned short As[2 * 256 * 64];   // 64 KiB
    __shared__ __align__(16) unsigned short Bs[2 * BN * 64];    // 64/32 KiB

    const int tid  = threadIdx.x;
    const int lane = tid & 63;
    const int wid  = tid >> 6;
    const int lr = lane & 15;
    const int lq = lane >> 4;
    const int mb = wid / WARPS_N;
    const int nb = wid % WARPS_N;

    // XCD-aware bijective swizzle (grid is a multiple of 8)
    const int nwg = (int)gridDim.x;
    const int bid = (int)blockIdx.x;
    const int swz = (bid & 7) * (nwg >> 3) + (bid >> 3);
    const int bx = swz % NBX;
    const int by = swz / NBX;
    const size_t aRow0 = (size_t)by * BM;
    const size_t bRow0 = (size_t)bx * BN;

    // staging source pointers: per-lane row + XOR-swizzled 16B column chunk
    const int sRow = tid >> 3;
    const int sChunk = ((tid & 7) ^ (sRow & 7)) << 3;
    const unsigned short* pA = A + (aRow0 + sRow) * (size_t)K + sChunk;
    const unsigned short* pB = B + (bRow0 + sRow) * (size_t)K + sChunk;

    // read-side constants
    const int swz0 = ((lq ^ (lr & 7)) << 3);
    const int swz1 = (((4 + lq) ^ (lr & 7)) << 3);
    const int AH  = (mb * WM) >> 7;            // wave's A half (no crossing)
    const int rA0 = (mb * WM) & 127;
    const int BHw = (nb * WN) / BH;            // wave's B half
    const int rB0 = (nb * WN) % BH;

    f32x4 acc[MF][NF];
    #pragma unroll
    for (int i_ = 0; i_ < MF; ++i_)
        #pragma unroll
        for (int j_ = 0; j_ < NF; ++j_)
            acc[i_][j_] = f32x4{0.f, 0.f, 0.f, 0.f};

    bf16x8 av[2][MF2][2];
    bf16x8 bv[2][NF2][2];

    // prologue: tile0 fully into buf0, tile1's A halves into buf1.
    // Then pre-issue the first quadrant's frag reads (av[0], bv[0]).
    STAGE_B(0, 0, 0); STAGE_B(0, 1, 0);
    STAGE_A(0, 0, 0); STAGE_A(0, 1, 0);
    STAGE_A(1, 0, 1); STAGE_A(1, 1, 1);
    WVM_N(4);                                   // tile0 drained; tile1-A in flight
    BAR();
    LDA(0, 0); LDB(0, 0);                       // 12/8 reads in flight into p1

    #pragma unroll 1
    for (int it = 0; it < K / 128; ++it) {
        const int t1 = 2 * it + 1;
        const int t2 = 2 * it + 2;
        const int t3 = 2 * it + 3;

        // ---- even tile 2it (buf0): Q=(0,0),(1,0),(1,1),(0,1) ----
        LDA(1, 0); STAGE_B(1, 0, t1);           // p1: read-ahead av[1]
        BAR(); WLG_A();
        MMA(0, 0);
        WVM_B1(); BAR();                        // publish B1(2it) [prev p6]

        LDB(1, 0); STAGE_B(1, 1, t1);           // p2: read-ahead bv[1]
        BAR(); WLG_B();
        MMA(1, 0);
        WVM_HALF(); BAR();                      // publish A(2it+1)+B0(2it+1)

        LDB(0, 1); STAGE_A(0, 0, t2);           // p3: read-ahead bv[0]<-buf1
        BAR(); WLG_B();
        MMA(1, 1);
        BAR();

        LDA(1, 1); STAGE_A(0, 1, t2);           // p4: read-ahead av[1]<-buf1
        BAR(); WLG_A();
        MMA(0, 1);
        BAR();

        // ---- odd tile 2it+1 (buf1): Q=(1,0),(0,0),(0,1),(1,1) ----
        LDA(0, 1); STAGE_B(0, 0, t2);           // p5: read-ahead av[0]<-buf1
        BAR(); WLG_A();
        MMA(1, 0);
        WVM_B1(); BAR();                        // publish B1(2it+1) [p2]

        LDB(1, 1); STAGE_B(0, 1, t2);           // p6: read-ahead bv[1]<-buf1
        BAR(); WLG_B();
        MMA(0, 0);
        WVM_HALF(); BAR();                      // publish A(2it+2)+B0(2it+2)

        LDB(0, 0); STAGE_A(1, 0, t3);           // p7: read-ahead bv[0]<-buf0
        BAR(); WLG_B();
        MMA(0, 1);
        BAR();

        LDA(0, 0); STAGE_A(1, 1, t3);           // p8: read-ahead av[0]<-buf0
        BAR(); WLG_A();
        MMA(1, 1);
        BAR();
    }

    // epilogue. C/D layout: col = lane&15, row = (lane>>4)*4 + reg
    #pragma unroll
    for (int mf = 0; mf < MF; ++mf) {
        #pragma unroll
        for (int nf = 0; nf < NF; ++nf) {
            const size_t col = bRow0 + (size_t)nb * WN + nf * 16 + lr;
            const float bvs = bias[col];
            #pragma unroll
            for (int r = 0; r < 4; ++r) {
                const size_t row = aRow0 + (size_t)mb * WM + mf * 16 + lq * 4 + r;
                float v = acc[mf][nf][r] + bvs;
                if constexpr (EPI == 0) {
                    ((unsigned short*)C)[row * (size_t)N + col] = f2bf(fast_gelu(v));
                } else {
                    ((float*)C)[row * (size_t)N + col] = v;
                }
            }
        }
    }
}

#undef GLL
#undef BAR
#undef WLG_N
#undef WVM_N
#undef WLG_A
#undef WLG_B
#undef WVM_B1
#undef WVM_HALF
#undef LDA
#undef LDB
#undef MMA
#undef STAGE_A
#undef STAGE_B

// ---------------- launch ----------------

extern "C" void kernel_launch(void* const* d_in, const int* in_sizes, int n_in,
                              void* d_out, int out_size, void* d_ws, size_t ws_size,
                              hipStream_t stream) {
    const float* x  = (const float*)d_in[0];   // [4,2048,1024]
    const float* W1 = (const float*)d_in[1];   // [4096,1024]
    const float* b1 = (const float*)d_in[2];   // [4096]
    const float* W2 = (const float*)d_in[3];   // [1024,4096]
    const float* b2 = (const float*)d_in[4];   // [1024]
    float* out = (float*)d_out;                // fp32 [4,2048,1024]

    const int M = 8192, EMB = 1024, FF = 4096;
    const int nW = FF * EMB;                   // 4194304

    char* ws = (char*)d_ws;
    float* part = (float*)ws;                                    // 1024 floats
    unsigned short* W1t = (unsigned short*)(ws + 16384);         // 8.39 MB
    unsigned short* W2t = W1t + (size_t)nW;                      // 8.39 MB
    unsigned short* xb  = W2t + (size_t)nW;                      // 16.78 MB
    unsigned short* h   = xb  + (size_t)M * EMB;                 // 67.1 MB

    abs_sum_cvt_kernel<<<1536, 256, 0, stream>>>((const float4*)W1, (const float4*)W2,
                                                 nW / 4, part,
                                                 (const float4*)x, (ushort4*)xb,
                                                 (M * EMB) / 4);
    ternarize_kernel<<<2048, 256, 0, stream>>>((const float4*)W1, (ushort4*)W1t,
                                               (const float4*)W2, (ushort4*)W2t,
                                               nW / 4, part, 1.0f / nW);

    // GEMM1: h[M,FF] = gelu(x[M,EMB] * W1t^T + b1), bf16 out.  grid 16x32=512
    gemm8p_kernel<0, 1024, 4096, 256, 128><<<dim3(512), dim3(512), 0, stream>>>(xb, W1t, b1, h);
    // GEMM2: out[M,EMB] = h[M,FF] * W2t^T + b2, fp32 out.      grid 8x32=256
    gemm8p_kernel<1, 4096, 1024, 128, 64><<<dim3(256), dim3(512), 0, stream>>>(h, W2t, b2, out);
}

// Round 3
// 257.951 us; speedup vs baseline: 1.0943x; 1.0943x over previous
//
#include <hip/hip_runtime.h>
#include <hip/hip_bf16.h>
#include <cstdint>
#include <cstddef>

typedef __bf16 bf16x8 __attribute__((ext_vector_type(8)));
typedef float  f32x4  __attribute__((ext_vector_type(4)));

__device__ __forceinline__ unsigned short f2bf(float f) {
    __hip_bfloat16 b = __float2bfloat16(f);
    return *reinterpret_cast<unsigned short*>(&b);
}

// fast GELU (tanh form), ~7 VALU ops, saturation-safe:
// g = x / (1 + exp2(x*(-2.30220795 - 0.10294314 x^2)))
__device__ __forceinline__ float fast_gelu(float x) {
    float x2 = x * x;
    float m  = x * __builtin_fmaf(x2, -0.10294314f, -2.30220795f);
    float e  = __builtin_amdgcn_exp2f(m);
    return x * __builtin_amdgcn_rcpf(1.0f + e);
}

// ---------------- aux kernels (unchanged) ----------------

__global__ void abs_sum_cvt_kernel(const float4* __restrict__ w0, const float4* __restrict__ w1,
                                   int n4w, float* __restrict__ part,
                                   const float4* __restrict__ x, ushort4* __restrict__ xb,
                                   int n4x) {
    int seg = (int)blockIdx.x >> 9;                // 0,1,2
    int b = (int)blockIdx.x & 511;
    if (seg == 2) {
        for (int i = b * blockDim.x + threadIdx.x; i < n4x; i += 512 * blockDim.x) {
            float4 v = x[i];
            ushort4 o;
            o.x = f2bf(v.x); o.y = f2bf(v.y); o.z = f2bf(v.z); o.w = f2bf(v.w);
            xb[i] = o;
        }
        return;
    }
    const float4* w = seg ? w1 : w0;
    float s = 0.0f;
    for (int i = b * blockDim.x + threadIdx.x; i < n4w; i += 512 * blockDim.x) {
        float4 v = w[i];
        s += fabsf(v.x) + fabsf(v.y) + fabsf(v.z) + fabsf(v.w);
    }
    #pragma unroll
    for (int o = 32; o > 0; o >>= 1) s += __shfl_down(s, o, 64);
    __shared__ float ps[4];
    int lane = threadIdx.x & 63, wid = threadIdx.x >> 6;
    if (lane == 0) ps[wid] = s;
    __syncthreads();
    if (threadIdx.x == 0) part[blockIdx.x] = ps[0] + ps[1] + ps[2] + ps[3];
}

__global__ void ternarize_kernel(const float4* __restrict__ w0, ushort4* __restrict__ t0,
                                 const float4* __restrict__ w1, ushort4* __restrict__ t1,
                                 int n4w, const float* __restrict__ part, float inv_n) {
    int seg = (int)blockIdx.x >> 10;               // 0 or 1
    int b = (int)blockIdx.x & 1023;

    float s = 0.0f;
    for (int j = threadIdx.x; j < 512; j += 256) s += part[seg * 512 + j];
    #pragma unroll
    for (int o = 32; o > 0; o >>= 1) s += __shfl_down(s, o, 64);
    __shared__ float ps[4];
    __shared__ float sscale;
    int lane = threadIdx.x & 63, wid = threadIdx.x >> 6;
    if (lane == 0) ps[wid] = s;
    __syncthreads();
    if (threadIdx.x == 0) {
        float tot = ps[0] + ps[1] + ps[2] + ps[3];
        sscale = fmaxf(tot * inv_n, 1e-8f);
    }
    __syncthreads();
    float inv = 1.0f / sscale;

    const float4* w = seg ? w1 : w0;
    ushort4* t = seg ? t1 : t0;
    for (int i = b * blockDim.x + threadIdx.x; i < n4w; i += 1024 * blockDim.x) {
        float4 v = w[i];
        ushort4 o;
        o.x = f2bf(fminf(fmaxf(rintf(v.x * inv), -1.0f), 1.0f));
        o.y = f2bf(fminf(fmaxf(rintf(v.y * inv), -1.0f), 1.0f));
        o.z = f2bf(fminf(fmaxf(rintf(v.z * inv), -1.0f), 1.0f));
        o.w = f2bf(fminf(fmaxf(rintf(v.w * inv), -1.0f), 1.0f));
        t[i] = o;
    }
}

// ---------------- 8-phase GEMM, DEEP stage pipeline ----------------
// NT: C[m][n] = sum_k A[m][k]*B[n][k].  BM=256, BK=64, 512 thr = 8 waves, dbuf LDS.
//
// Iteration i: reads tile E=2i (buf0) at p1-4, tile O=2i+1 (buf1) at p5-8.
// Reads are in-phase (issue -> barrier -> lgkm(0) -> MFMA): the barrier wait
// hides ds_read latency (m201 form).  Read phases per tile:
//   p1: LDA(0)+LDB(0), MMA(0,0);  p2: LDA(1), MMA(1,0);
//   p3: LDB(1), MMA(1,1);         p4: (none), MMA(0,1).
// => A halves of a buffer are last read at p2/p6, B halves at p3/p7.
//
// Stage stream (1-2 half-tiles/phase), placed in the WAR-free windows:
//   p1: B1 of O_i (buf1)     [buf1 B last read prev p7]
//   p3: A0 E'=2i+2 (buf0)    [buf0 A last read p2]
//   p4: A1 E' + B0 E'        [buf0 B last read p3]
//   p5: B1 E'
//   p7: A0 O'=2i+3 (buf1)    [buf1 A last read p6]
//   p8: A1 O' + B0 O'        [buf1 B last read p7]
// Publication waits: ONLY two per iteration, both with >=3.5-phase distance
// to the newest waited-on load (HBM latency fully hidden):
//   p4-end vmcnt(6|5): drains {p7',p8' prev, p1} = O_i's 4 halves -> p5-8 safe
//   p8-end vmcnt(6|5): drains {p3,p4,p5} = E'{i+1}'s 4 halves    -> p1-4 safe
// (6 for BN=256 [2 loads/B-half], 5 for BN=128 [1 load/B-half].)
// Prologue: stage t0 fully + t1 minus B1; wait = same count -> t0 published;
// t1's B1 rides p1 of iter 0.  Last iteration wraps stage tiles mod KT
// (harmless re-stage after final reads).  NEVER vmcnt(0) in the loop.
// LDS 16B-chunk XOR swizzle via pre-swizzled GLOBAL source column (dest of
// global_load_lds stays linear); reads use same XOR -> zero bank conflicts.

#define GLL(SRC, DST) __builtin_amdgcn_global_load_lds( \
    (const __attribute__((address_space(1))) void*)(SRC), \
    (__attribute__((address_space(3))) void*)(DST), 16, 0, 0)

#define BAR() do { asm volatile("" ::: "memory"); \
    __builtin_amdgcn_sched_barrier(0); \
    __builtin_amdgcn_s_barrier(); \
    __builtin_amdgcn_sched_barrier(0); \
    asm volatile("" ::: "memory"); } while (0)

#define WLG0() do { asm volatile("s_waitcnt lgkmcnt(0)" ::: "memory"); \
    __builtin_amdgcn_sched_barrier(0); } while (0)
#define WVM_N(NN) do { asm volatile("s_waitcnt vmcnt(" #NN ")" ::: "memory"); \
    __builtin_amdgcn_sched_barrier(0); } while (0)
#define WVM_TILE() do { if constexpr (SBL == 2) WVM_N(6); else WVM_N(5); } while (0)

#define LDA(MS, BUF) do { \
    _Pragma("unroll") \
    for (int f_ = 0; f_ < MF2; ++f_) { \
        const unsigned short* p_ = &As[(BUF)*16384 + AH*8192 + (rA0 + (MS)*(WM/2) + f_*16 + lr)*64]; \
        av[MS][f_][0] = *(const bf16x8*)(p_ + swz0); \
        av[MS][f_][1] = *(const bf16x8*)(p_ + swz1); \
    } \
} while (0)

#define LDB(NS, BUF) do { \
    _Pragma("unroll") \
    for (int g_ = 0; g_ < NF2; ++g_) { \
        const unsigned short* p_ = &Bs[(BUF)*(BN*64) + BHw*(BH*64) + (rB0 + (NS)*32 + g_*16 + lr)*64]; \
        bv[NS][g_][0] = *(const bf16x8*)(p_ + swz0); \
        bv[NS][g_][1] = *(const bf16x8*)(p_ + swz1); \
    } \
} while (0)

#define MMA(MS, NS) do { \
    __builtin_amdgcn_s_setprio(1); \
    _Pragma("unroll") \
    for (int f_ = 0; f_ < MF2; ++f_) { \
        _Pragma("unroll") \
        for (int g_ = 0; g_ < NF2; ++g_) { \
            acc[(MS)*MF2 + f_][(NS)*NF2 + g_] = __builtin_amdgcn_mfma_f32_16x16x32_bf16( \
                av[MS][f_][0], bv[NS][g_][0], acc[(MS)*MF2 + f_][(NS)*NF2 + g_], 0, 0, 0); \
            acc[(MS)*MF2 + f_][(NS)*NF2 + g_] = __builtin_amdgcn_mfma_f32_16x16x32_bf16( \
                av[MS][f_][1], bv[NS][g_][1], acc[(MS)*MF2 + f_][(NS)*NF2 + g_], 0, 0, 0); \
        } \
    } \
    __builtin_amdgcn_s_setprio(0); \
} while (0)

#define STAGE_A(BUF, H, T) do { \
    const unsigned short* s_ = pA + (size_t)((H)*128)*K + (((T) & (KT-1)) << 6); \
    GLL(s_,                 &As[(BUF)*16384 + (H)*8192 + tid*8]); \
    GLL(s_ + (size_t)64*K,  &As[(BUF)*16384 + (H)*8192 + 4096 + tid*8]); \
} while (0)

#define STAGE_BH(BUF, H, T) do { \
    const unsigned short* s_ = pB + (size_t)((H)*BH)*K + (((T) & (KT-1)) << 6); \
    GLL(s_, &Bs[(BUF)*(BN*64) + (H)*(BH*64) + tid*8]); \
    if constexpr (BN == 256) { \
        GLL(s_ + (size_t)64*K, &Bs[(BUF)*(BN*64) + (H)*(BH*64) + 4096 + tid*8]); \
    } \
} while (0)

// EPI==0: C = bf16, bias + fast GELU.  EPI==1: C = fp32, bias.
// BN=256 -> waves 2Mx4N (wave tile 128x64).  BN=128 -> waves 4Mx2N (64x64).
template <int EPI, int K, int N, int BN, int WM>
__global__ __launch_bounds__(512, 2)
void gemm8p_kernel(const unsigned short* __restrict__ A,
                   const unsigned short* __restrict__ B,
                   const float* __restrict__ bias,
                   void* __restrict__ C) {
    constexpr int BM = 256;
    constexpr int WN = 64;
    constexpr int WARPS_N = BN / WN;           // 4 or 2
    constexpr int MF = WM / 16;                // 8 or 4
    constexpr int NF = WN / 16;                // 4
    constexpr int MF2 = MF / 2;                // 4 or 2
    constexpr int NF2 = NF / 2;                // 2
    constexpr int BH = (BN == 256) ? 128 : 64; // rows per B half-tile
    constexpr int SBL = (BN == 256) ? 2 : 1;   // loads per B half-tile stage
    constexpr int KT = K / 64;                 // K-tiles (power of 2)
    constexpr int NBX = N / BN;
    static_assert((BM / WM) * WARPS_N == 8, "8 waves");
    static_assert((KT & (KT - 1)) == 0, "KT pow2");

    __shared__ __align__(16) unsigned short As[2 * 256 * 64];   // 64 KiB
    __shared__ __align__(16) unsigned short Bs[2 * BN * 64];    // 64/32 KiB

    const int tid  = threadIdx.x;
    const int lane = tid & 63;
    const int wid  = tid >> 6;
    const int lr = lane & 15;
    const int lq = lane >> 4;
    const int mb = wid / WARPS_N;
    const int nb = wid % WARPS_N;

    // XCD-aware bijective swizzle (grid is a multiple of 8)
    const int nwg = (int)gridDim.x;
    const int bid = (int)blockIdx.x;
    const int swz = (bid & 7) * (nwg >> 3) + (bid >> 3);
    const int bx = swz % NBX;
    const int by = swz / NBX;
    const size_t aRow0 = (size_t)by * BM;
    const size_t bRow0 = (size_t)bx * BN;

    // staging source pointers: per-lane row + XOR-swizzled 16B column chunk
    const int sRow = tid >> 3;
    const int sChunk = ((tid & 7) ^ (sRow & 7)) << 3;
    const unsigned short* pA = A + (aRow0 + sRow) * (size_t)K + sChunk;
    const unsigned short* pB = B + (bRow0 + sRow) * (size_t)K + sChunk;

    // read-side constants
    const int swz0 = ((lq ^ (lr & 7)) << 3);
    const int swz1 = (((4 + lq) ^ (lr & 7)) << 3);
    const int AH  = (mb * WM) >> 7;            // wave's A half (no crossing)
    const int rA0 = (mb * WM) & 127;
    const int BHw = (nb * WN) / BH;            // wave's B half
    const int rB0 = (nb * WN) % BH;

    f32x4 acc[MF][NF];
    #pragma unroll
    for (int i_ = 0; i_ < MF; ++i_)
        #pragma unroll
        for (int j_ = 0; j_ < NF; ++j_)
            acc[i_][j_] = f32x4{0.f, 0.f, 0.f, 0.f};

    bf16x8 av[2][MF2][2];
    bf16x8 bv[2][NF2][2];

    // prologue: tile0 fully (buf0) + tile1 minus B1 (buf1).
    // wait leaves exactly the t1-partial loads outstanding -> t0 published.
    STAGE_A(0, 0, 0); STAGE_A(0, 1, 0); STAGE_BH(0, 0, 0); STAGE_BH(0, 1, 0);
    STAGE_A(1, 0, 1); STAGE_A(1, 1, 1); STAGE_BH(1, 0, 1);
    WVM_TILE();
    BAR();

    #pragma unroll 1
    for (int it = 0; it < K / 128; ++it) {
        const int t1 = 2 * it + 1;
        const int t2 = 2 * it + 2;
        const int t3 = 2 * it + 3;

        // ---- even tile 2it (buf0) ----
        LDA(0, 0); LDB(0, 0);                   // p1
        STAGE_BH(1, 1, t1);                     //   B1 of O_i (buf1)
        BAR(); WLG0();
        MMA(0, 0);
        BAR();

        LDA(1, 0);                              // p2
        BAR(); WLG0();
        MMA(1, 0);
        BAR();

        LDB(1, 0);                              // p3
        STAGE_A(0, 0, t2);                      //   A0 E' (buf0)
        BAR(); WLG0();
        MMA(1, 1);
        BAR();

        STAGE_A(0, 1, t2); STAGE_BH(0, 0, t2);  // p4: A1 + B0 E'
        BAR();
        MMA(0, 1);
        WVM_TILE();                             //   publish O_i (prev p7,p8 + p1)
        BAR();

        // ---- odd tile 2it+1 (buf1) ----
        LDA(0, 1); LDB(0, 1);                   // p5
        STAGE_BH(0, 1, t2);                     //   B1 E' (buf0)
        BAR(); WLG0();
        MMA(0, 0);
        BAR();

        LDA(1, 1);                              // p6
        BAR(); WLG0();
        MMA(1, 0);
        BAR();

        LDB(1, 1);                              // p7
        STAGE_A(1, 0, t3);                      //   A0 O' (buf1)
        BAR(); WLG0();
        MMA(1, 1);
        BAR();

        STAGE_A(1, 1, t3); STAGE_BH(1, 0, t3);  // p8: A1 + B0 O'
        BAR();
        MMA(0, 1);
        WVM_TILE();                             //   publish E'_{i+1} (p3,p4,p5)
        BAR();
    }

    WVM_N(0);                                   // retire dangling wrap stages

    // epilogue. C/D layout: col = lane&15, row = (lane>>4)*4 + reg
    #pragma unroll
    for (int mf = 0; mf < MF; ++mf) {
        #pragma unroll
        for (int nf = 0; nf < NF; ++nf) {
            const size_t col = bRow0 + (size_t)nb * WN + nf * 16 + lr;
            const float bvs = bias[col];
            #pragma unroll
            for (int r = 0; r < 4; ++r) {
                const size_t row = aRow0 + (size_t)mb * WM + mf * 16 + lq * 4 + r;
                float v = acc[mf][nf][r] + bvs;
                if constexpr (EPI == 0) {
                    ((unsigned short*)C)[row * (size_t)N + col] = f2bf(fast_gelu(v));
                } else {
                    ((float*)C)[row * (size_t)N + col] = v;
                }
            }
        }
    }
}

#undef GLL
#undef BAR
#undef WLG0
#undef WVM_N
#undef WVM_TILE
#undef LDA
#undef LDB
#undef MMA
#undef STAGE_A
#undef STAGE_BH

// ---------------- launch ----------------

extern "C" void kernel_launch(void* const* d_in, const int* in_sizes, int n_in,
                              void* d_out, int out_size, void* d_ws, size_t ws_size,
                              hipStream_t stream) {
    const float* x  = (const float*)d_in[0];   // [4,2048,1024]
    const float* W1 = (const float*)d_in[1];   // [4096,1024]
    const float* b1 = (const float*)d_in[2];   // [4096]
    const float* W2 = (const float*)d_in[3];   // [1024,4096]
    const float* b2 = (const float*)d_in[4];   // [1024]
    float* out = (float*)d_out;                // fp32 [4,2048,1024]

    const int M = 8192, EMB = 1024, FF = 4096;
    const int nW = FF * EMB;                   // 4194304

    char* ws = (char*)d_ws;
    float* part = (float*)ws;                                    // 1024 floats
    unsigned short* W1t = (unsigned short*)(ws + 16384);         // 8.39 MB
    unsigned short* W2t = W1t + (size_t)nW;                      // 8.39 MB
    unsigned short* xb  = W2t + (size_t)nW;                      // 16.78 MB
    unsigned short* h   = xb  + (size_t)M * EMB;                 // 67.1 MB

    abs_sum_cvt_kernel<<<1536, 256, 0, stream>>>((const float4*)W1, (const float4*)W2,
                                                 nW / 4, part,
                                                 (const float4*)x, (ushort4*)xb,
                                                 (M * EMB) / 4);
    ternarize_kernel<<<2048, 256, 0, stream>>>((const float4*)W1, (ushort4*)W1t,
                                               (const float4*)W2, (ushort4*)W2t,
                                               nW / 4, part, 1.0f / nW);

    // GEMM1: h[M,FF] = gelu(x[M,EMB] * W1t^T + b1), bf16 out.  grid 16x32=512
    gemm8p_kernel<0, 1024, 4096, 256, 128><<<dim3(512), dim3(512), 0, stream>>>(xb, W1t, b1, h);
    // GEMM2: out[M,EMB] = h[M,FF] * W2t^T + b2, fp32 out.      grid 8x32=256
    gemm8p_kernel<1, 4096, 1024, 128, 64><<<dim3(256), dim3(512), 0, stream>>>(h, W2t, b2, out);
}